// Round 4
// baseline (153.971 us; speedup 1.0000x reference)
//
#include <hip/hip_runtime.h>
#include <hip/hip_bf16.h>
#include <stdint.h>

#define TS 1024   // T
#define CS 1024   // C
#define NH 16
#define DHEAD 64
#define NBATCH 2
#define EPSV 1e-5f
#define MEG 1048576

typedef __bf16 bf16x8 __attribute__((ext_vector_type(8)));
typedef __bf16 bf16x4 __attribute__((ext_vector_type(4)));
typedef float  f32x4  __attribute__((ext_vector_type(4)));

#define MFMA(a, b, c) __builtin_amdgcn_mfma_f32_16x16x32_bf16((a), (b), (c), 0, 0, 0)

__device__ __forceinline__ float bf2f(ushort u){
  union { uint32_t i; float f; } v; v.i = ((uint32_t)u) << 16; return v.f;
}
__device__ __forceinline__ ushort f2bf(float f){
  union { float f; uint32_t i; } v; v.f = f;
  uint32_t r = v.i + 0x7FFFu + ((v.i >> 16) & 1u);
  return (ushort)(r >> 16);
}

// async global->LDS, 16B per lane. LDS dest wave-uniform base + lane*16B (linear);
// global src per-lane (enables pre-swizzled-source LDS layouts).
__device__ __forceinline__ void gl_lds16(const ushort* g, ushort* l) {
  __builtin_amdgcn_global_load_lds(
      (const __attribute__((address_space(1))) void*)g,
      (__attribute__((address_space(3))) void*)l, 16, 0, 0);
}

// ---------------- fused cast fp32 -> bf16 of all 7 tensors ----------------
__global__ __launch_bounds__(256)
void cast_all(const float* __restrict__ x,
              const float* __restrict__ Wq, const float* __restrict__ Wk,
              const float* __restrict__ Wv, const float* __restrict__ Wq2,
              const float* __restrict__ Wk2, const float* __restrict__ Wo,
              ushort* __restrict__ xb, ushort* __restrict__ wcat)
{
  const int XC = 524288, TOT = 2097152;
  for (int idx = blockIdx.x * 256 + threadIdx.x; idx < TOT; idx += 524288) {
    const float* s; ushort* d; int c;
    if (idx < XC) { s = x; d = xb; c = idx; }
    else {
      int r = idx - XC; int w = r >> 18; c = r & 262143;
      switch (w) {
        case 0:  s = Wq;  d = wcat;           break;
        case 1:  s = Wk;  d = wcat + 1*MEG;   break;
        case 2:  s = Wv;  d = wcat + 4*MEG;   break;
        case 3:  s = Wq2; d = wcat + 2*MEG;   break;
        case 4:  s = Wk2; d = wcat + 3*MEG;   break;
        default: s = Wo;  d = wcat + 5*MEG;   break;
      }
    }
    float4 v = *(const float4*)(s + (size_t)c * 4);
    ushort4 o; o.x = f2bf(v.x); o.y = f2bf(v.y); o.z = f2bf(v.z); o.w = f2bf(v.w);
    *(ushort4*)(d + (size_t)c * 4) = o;
  }
}

// ---------------- generic bf16 B^T GEMM (global_load_lds staging) ----------------
#define BM 128
#define BN 128
#define BKK 32

template<int EPI>
__global__ __launch_bounds__(256, 2)
void gemm_bt(const ushort* __restrict__ A, const ushort* __restrict__ Bt,
             void* __restrict__ Cout,
             int M, int N, int K, int lda, int ldb, int ldc,
             long sA1, long sA2, long sB1, long sB2, long sC1, long sC2,
             float scale)
{
  __shared__ ushort a_s[BM * BKK];
  __shared__ ushort b_s[BN * BKK];

  const int z = blockIdx.z, zh = z >> 4, zl = z & 15;
  A  += (size_t)zh * sA1 + (size_t)zl * sA2;
  Bt += (size_t)zh * sB1 + (size_t)zl * sB2;

  const int n0 = blockIdx.x * BN;
  const int m0 = blockIdx.y * BM;

  const int t  = threadIdx.x;
  const int w  = t >> 6, l = t & 63;
  const int wr = w >> 1, wc = w & 1;
  const int l15 = l & 15, l4 = l >> 4;

  const int rs = l >> 2;
  const int c8 = (l & 3) * 8;

  f32x4 acc[4][4] = {};

  for (int k0 = 0; k0 < K; k0 += BKK) {
    #pragma unroll
    for (int j = 0; j < 2; ++j) {
      int ch = w * 2 + j;
      int r  = ch * 16 + rs;
      gl_lds16(&A [(size_t)(m0 + r) * lda + k0 + c8], &a_s[ch * 512]);
      gl_lds16(&Bt[(size_t)(n0 + r) * ldb + k0 + c8], &b_s[ch * 512]);
    }
    __syncthreads();

    bf16x8 af[4], bfr[4];
    #pragma unroll
    for (int mi = 0; mi < 4; ++mi)
      af[mi] = *(const bf16x8*)&a_s[(wr * 64 + mi * 16 + l15) * BKK + l4 * 8];
    #pragma unroll
    for (int ni = 0; ni < 4; ++ni)
      bfr[ni] = *(const bf16x8*)&b_s[(wc * 64 + ni * 16 + l15) * BKK + l4 * 8];

    #pragma unroll
    for (int mi = 0; mi < 4; ++mi)
      #pragma unroll
      for (int ni = 0; ni < 4; ++ni)
        acc[mi][ni] = MFMA(af[mi], bfr[ni], acc[mi][ni]);

    __syncthreads();
  }

  #pragma unroll
  for (int mi = 0; mi < 4; ++mi) {
    #pragma unroll
    for (int ni = 0; ni < 4; ++ni) {
      int col  = n0 + wc * 64 + ni * 16 + l15;
      int row0 = m0 + wr * 64 + mi * 16 + l4 * 4;
      if (EPI == 0) {
        ushort* C = (ushort*)Cout + (size_t)zh * sC1 + (size_t)zl * sC2;
        #pragma unroll
        for (int e = 0; e < 4; ++e)
          C[(size_t)(row0 + e) * ldc + col] = f2bf(acc[mi][ni][e] * scale);
      } else {
        float* C = (float*)Cout + (size_t)zh * sC1 + (size_t)zl * sC2;
        #pragma unroll
        for (int e = 0; e < 4; ++e)
          C[(size_t)(row0 + e) * ldc + col] = acc[mi][ni][e] * scale;
      }
    }
  }
}

// ---------------- fused projection GEMM: [x]@[Wq;Wk;Wq2;Wk2;Wv]^T ----------------
// seg 0..3 -> q/k/q2/k2 row-major (q,q2 pre-scaled by 1/8, exact in bf16);
// seg 1,3 additionally write transposed K/K2 ([z][64][T], like V) for the gram kernel;
// seg 4 -> V transposed per head.
__global__ __launch_bounds__(256, 2)
void gemm_proj(const ushort* __restrict__ A, const ushort* __restrict__ Bt,
               ushort* __restrict__ qb, ushort* __restrict__ kb,
               ushort* __restrict__ q2b, ushort* __restrict__ k2b,
               ushort* __restrict__ vtb,
               ushort* __restrict__ ktb, ushort* __restrict__ k2tb)
{
  __shared__ ushort a_s[BM * BKK];
  __shared__ ushort b_s[BN * BKK];

  const int n0 = blockIdx.x * BN;
  const int m0 = blockIdx.y * BM;

  const int t  = threadIdx.x;
  const int w  = t >> 6, l = t & 63;
  const int wr = w >> 1, wc = w & 1;
  const int l15 = l & 15, l4 = l >> 4;

  const int rs = l >> 2;
  const int c8 = (l & 3) * 8;

  f32x4 acc[4][4] = {};

  for (int k0 = 0; k0 < CS; k0 += BKK) {
    #pragma unroll
    for (int j = 0; j < 2; ++j) {
      int ch = w * 2 + j;
      int r  = ch * 16 + rs;
      gl_lds16(&A [(size_t)(m0 + r) * CS + k0 + c8], &a_s[ch * 512]);
      gl_lds16(&Bt[(size_t)(n0 + r) * CS + k0 + c8], &b_s[ch * 512]);
    }
    __syncthreads();

    bf16x8 af[4], bfr[4];
    #pragma unroll
    for (int mi = 0; mi < 4; ++mi)
      af[mi] = *(const bf16x8*)&a_s[(wr * 64 + mi * 16 + l15) * BKK + l4 * 8];
    #pragma unroll
    for (int ni = 0; ni < 4; ++ni)
      bfr[ni] = *(const bf16x8*)&b_s[(wc * 64 + ni * 16 + l15) * BKK + l4 * 8];

    #pragma unroll
    for (int mi = 0; mi < 4; ++mi)
      #pragma unroll
      for (int ni = 0; ni < 4; ++ni)
        acc[mi][ni] = MFMA(af[mi], bfr[ni], acc[mi][ni]);

    __syncthreads();
  }

  #pragma unroll
  for (int mi = 0; mi < 4; ++mi) {
    #pragma unroll
    for (int ni = 0; ni < 4; ++ni) {
      int col  = n0 + wc * 64 + ni * 16 + l15;
      int row0 = m0 + wr * 64 + mi * 16 + l4 * 4;
      int seg  = col >> 10, cc = col & (CS - 1);
      if (seg < 4) {
        ushort* dst = (seg == 0) ? qb : (seg == 1) ? kb : (seg == 2) ? q2b : k2b;
        float sc = (seg & 1) ? 1.f : 0.125f;   // fold 1/sqrt(Dh) into q, q2
        #pragma unroll
        for (int e = 0; e < 4; ++e)
          dst[(size_t)(row0 + e) * CS + cc] = f2bf(acc[mi][ni][e] * sc);
        if (seg == 1 || seg == 3) {
          int bb = row0 >> 10, tt = row0 & (TS - 1);
          int hh = cc >> 6, dd = cc & (DHEAD - 1);
          ushort* td = (seg == 1) ? ktb : k2tb;
          ushort4 o;
          o.x = f2bf(acc[mi][ni][0]); o.y = f2bf(acc[mi][ni][1]);
          o.z = f2bf(acc[mi][ni][2]); o.w = f2bf(acc[mi][ni][3]);
          *(ushort4*)&td[(((size_t)(bb * NH + hh) * DHEAD + dd) * TS) + tt] = o;
        }
      } else {
        int bb = row0 >> 10, tt = row0 & (TS - 1);
        int hh = cc >> 6, dd = cc & (DHEAD - 1);
        ushort4 o;
        o.x = f2bf(acc[mi][ni][0]); o.y = f2bf(acc[mi][ni][1]);
        o.z = f2bf(acc[mi][ni][2]); o.w = f2bf(acc[mi][ni][3]);
        *(ushort4*)&vtb[(((size_t)(bb * NH + hh) * DHEAD + dd) * TS) + tt] = o;
      }
    }
  }
}

// ---------------- Gram kernel: G = K^T K (64x64, bf16 out) + colsum(K) ----------
// grid = 64: blockIdx.x = z*2 + mat. Reads transposed K layout [z][64 d][T].
__global__ __launch_bounds__(256, 2)
void gram(const ushort* __restrict__ ktb, const ushort* __restrict__ k2tb,
          ushort* __restrict__ g1b, ushort* __restrict__ g2b,
          float* __restrict__ csb)
{
  __shared__ ushort t_s[64 * 128];   // [64 d][128 t], granule-swizzled g ^= d&15

  const int mat = blockIdx.x & 1, z = blockIdx.x >> 1;
  const ushort* S = (mat ? k2tb : ktb) + (size_t)z * DHEAD * TS;

  const int t = threadIdx.x, w = t >> 6, l = t & 63;
  const int l15 = l & 15, l4 = l >> 4;

  f32x4 acc[4] = {};
  float csacc = 0.f;

  for (int tt = 0; tt < 8; ++tt) {
    const int t0 = tt * 128;
    __syncthreads();
    #pragma unroll
    for (int i = 0; i < 4; ++i) {
      int issue = w * 4 + i;
      int row = issue * 4 + l4;
      int gs  = l15 ^ (row & 15);
      gl_lds16(&S[(size_t)row * TS + t0 + gs * 8], &t_s[issue * 512]);
    }
    __syncthreads();

    // colsum partial: lane handles row w*16+l15, t-granules l4*4..+3
    {
      int r = w * 16 + l15;
      #pragma unroll
      for (int j = 0; j < 4; ++j) {
        int gg = ((l4 * 4 + j) ^ (r & 15)) * 8;
        uint4 vv = *(const uint4*)&t_s[r * 128 + gg];
        const ushort* pu = (const ushort*)&vv;
        #pragma unroll
        for (int e2 = 0; e2 < 8; ++e2) csacc += bf2f(pu[e2]);
      }
    }

    #pragma unroll
    for (int ks = 0; ks < 4; ++ks) {
      int ar = w * 16 + l15;
      bf16x8 af = *(const bf16x8*)&t_s[ar * 128 + ((ks * 4 + l4) ^ (ar & 15)) * 8];
      #pragma unroll
      for (int ni = 0; ni < 4; ++ni) {
        int br = ni * 16 + l15;
        bf16x8 bf_ = *(const bf16x8*)&t_s[br * 128 + ((ks * 4 + l4) ^ (br & 15)) * 8];
        acc[ni] = MFMA(af, bf_, acc[ni]);
      }
    }
  }

  csacc += __shfl_xor(csacc, 16);
  csacc += __shfl_xor(csacc, 32);
  if (l4 == 0)
    csb[(mat * 32 + z) * 64 + w * 16 + l15] = csacc;

  ushort* G = (mat ? g2b : g1b) + (size_t)z * 4096;
  #pragma unroll
  for (int ni = 0; ni < 4; ++ni)
    #pragma unroll
    for (int e = 0; e < 4; ++e)
      G[(w * 16 + l4 * 4 + e) * 64 + ni * 16 + l15] = f2bf(acc[ni][e]);
}

// ---------------- fused attention v2 ----------------
// Block: one head z, one 64-row Q-tile. 4 waves; wave w owns rows [w*16, w*16+16).
// Stats via Gram trick: mu = q.cs/T ; sumsq = q^T G q (U = Q@G by MFMA).
// Tile loop (KVBLK=64): 2 barriers/tile, all softmax ops wave-local,
// P write->PV read is wave-local LDS (no barrier).
__global__ __launch_bounds__(256, 4)
void attn_fused(const ushort* __restrict__ qb, const ushort* __restrict__ kb,
                const ushort* __restrict__ q2b, const ushort* __restrict__ k2b,
                const ushort* __restrict__ vtb, ushort* __restrict__ yb,
                const ushort* __restrict__ g1b, const ushort* __restrict__ g2b,
                const float* __restrict__ csb,
                const float* __restrict__ mixture, const float* __restrict__ qsc)
{
  __shared__ ushort k_s [4096];     // K tile  [64 t][64 d] swz g^=t&7   (Q  in phase A)
  __shared__ ushort k2_s[4096];     // K2 tile                            (Q2 in phase A)
  __shared__ ushort v_s [4096];     // V tile  [64 d][64 t] swz g^=d&7   (G1 in phase A)
  __shared__ ushort p_s [64 * 68];  // P tile  [64 r][64+4 pad]          (G2 in phase A)

  const int idx  = blockIdx.x;
  const int xcd  = idx & 7, slot = idx >> 3;
  const int z    = ((slot >> 4) << 3) + xcd;     // head id 0..31, affine to XCD
  const int qt   = 15 - (slot & 15);             // big q-tiles first
  const int b    = z >> 4, h = z & 15;
  const int m0   = qt * 64;

  const ushort* Q  = qb  + (size_t)b * TS * CS + h * DHEAD;
  const ushort* Q2 = q2b + (size_t)b * TS * CS + h * DHEAD;
  const ushort* K  = kb  + (size_t)b * TS * CS + h * DHEAD;
  const ushort* K2 = k2b + (size_t)b * TS * CS + h * DHEAD;
  const ushort* Vt = vtb + (size_t)z * DHEAD * TS;
  const ushort* G1 = g1b + (size_t)z * 4096;
  const ushort* G2 = g2b + (size_t)z * 4096;
  ushort* Y = yb + (size_t)b * TS * CS + h * DHEAD;

  const int t = threadIdx.x, w = t >> 6, l = t & 63;
  const int l15 = l & 15, l4 = l >> 4;
  const int r8 = l >> 3, g7 = l & 7;

  const float gm = 1.f / (1.f + __expf(-mixture[0]));
  const float mq = gm * qsc[0];
  const float om = 1.f - gm;

  // ---- phase A: stage Q, Q2, G1, G2 (granule-swizzled) ----
  #pragma unroll
  for (int i = 0; i < 2; ++i) {
    int issue = w * 2 + i;
    int row = issue * 8 + r8;
    int gs  = g7 ^ (row & 7);
    gl_lds16(&Q [(size_t)(m0 + row) * CS + gs * 8], &k_s [issue * 512]);
    gl_lds16(&Q2[(size_t)(m0 + row) * CS + gs * 8], &k2_s[issue * 512]);
    gl_lds16(&G1[row * 64 + gs * 8], &v_s[issue * 512]);
    gl_lds16(&G2[row * 64 + gs * 8], &p_s[issue * 512]);
  }
  __syncthreads();

  // Q fragments (A-frag: row w*16+l15, k-slice ks*32+l4*8)
  const int qrow = w * 16 + l15;
  bf16x8 fq[2], fq2[2];
  #pragma unroll
  for (int ks = 0; ks < 2; ++ks) {
    int gg = ((ks * 4 + l4) ^ (qrow & 7)) * 8;
    fq [ks] = *(const bf16x8*)&k_s [qrow * 64 + gg];
    fq2[ks] = *(const bf16x8*)&k2_s[qrow * 64 + gg];
  }

  // U = Q @ G (G symmetric; B-frag rows = G rows)
  f32x4 U1[4] = {}, U2[4] = {};
  #pragma unroll
  for (int ks = 0; ks < 2; ++ks) {
    #pragma unroll
    for (int ni = 0; ni < 4; ++ni) {
      int gr = ni * 16 + l15;
      int gg = ((ks * 4 + l4) ^ (gr & 7)) * 8;
      bf16x8 bg1 = *(const bf16x8*)&v_s[gr * 64 + gg];
      bf16x8 bg2 = *(const bf16x8*)&p_s[gr * 64 + gg];
      U1[ni] = MFMA(fq [ks], bg1, U1[ni]);
      U2[ni] = MFMA(fq2[ks], bg2, U2[ni]);
    }
  }

  float cs1[4], cs2[4];
  #pragma unroll
  for (int ni = 0; ni < 4; ++ni) {
    cs1[ni] = csb[z * 64 + ni * 16 + l15];
    cs2[ni] = csb[2048 + z * 64 + ni * 16 + l15];
  }

  // per-row stats: sumsq = sum_d U[r][d]*q[r][d] ; mudot = sum_d q[r][d]*cs[d]
  float mu1[4], iv1[4], mu2[4], iv2[4];
  #pragma unroll
  for (int e = 0; e < 4; ++e) {
    int rl = w * 16 + l4 * 4 + e;
    float ssq1 = 0.f, md1 = 0.f, ssq2 = 0.f, md2 = 0.f;
    #pragma unroll
    for (int ni = 0; ni < 4; ++ni) {
      int d  = ni * 16 + l15;
      int ad = rl * 64 + (((d >> 3) ^ (rl & 7)) << 3) + (d & 7);
      float qv1 = bf2f(k_s[ad]);
      float qv2 = bf2f(k2_s[ad]);
      ssq1 = fmaf(U1[ni][e], qv1, ssq1); md1 = fmaf(qv1, cs1[ni], md1);
      ssq2 = fmaf(U2[ni][e], qv2, ssq2); md2 = fmaf(qv2, cs2[ni], md2);
    }
    #pragma unroll
    for (int o = 1; o <= 8; o <<= 1) {
      ssq1 += __shfl_xor(ssq1, o); md1 += __shfl_xor(md1, o);
      ssq2 += __shfl_xor(ssq2, o); md2 += __shfl_xor(md2, o);
    }
    float m1 = md1 * (1.f / TS), m2 = md2 * (1.f / TS);
    float v1 = (ssq1 - (float)TS * m1 * m1) * (1.f / (TS - 1));
    float v2 = (ssq2 - (float)TS * m2 * m2) * (1.f / (TS - 1));
    mu1[e] = m1; iv1[e] = 1.f / (sqrtf(fmaxf(v1, 0.f)) + EPSV);
    mu2[e] = m2; iv2[e] = 1.f / (sqrtf(fmaxf(v2, 0.f)) + EPSV);
  }

  // ---- tile loop: online softmax + PV ----
  float mrow[4], lrow[4];
  #pragma unroll
  for (int e = 0; e < 4; ++e) { mrow[e] = -INFINITY; lrow[e] = 0.f; }
  f32x4 accO[4] = {};

  for (int ct = 0; ct <= qt; ++ct) {
    const int t0 = ct * 64;
    __syncthreads();                             // prev-tile LDS reads done
    #pragma unroll
    for (int i = 0; i < 2; ++i) {
      int issue = w * 2 + i;
      int row = issue * 8 + r8;
      int gs  = g7 ^ (row & 7);
      gl_lds16(&K [(size_t)(t0 + row) * CS + gs * 8], &k_s [issue * 512]);
      gl_lds16(&K2[(size_t)(t0 + row) * CS + gs * 8], &k2_s[issue * 512]);
      gl_lds16(&Vt[(size_t)row * TS + t0 + gs * 8], &v_s[issue * 512]);
    }
    __syncthreads();                             // tiles staged

    // QK^T for both matrices (wave rows x 64 cols)
    f32x4 a1[4] = {}, a2[4] = {};
    #pragma unroll
    for (int ks = 0; ks < 2; ++ks) {
      bf16x8 bk[4], bk2[4];
      #pragma unroll
      for (int ni = 0; ni < 4; ++ni) {
        int j  = ni * 16 + l15;
        int gg = ((ks * 4 + l4) ^ (j & 7)) * 8;
        bk [ni] = *(const bf16x8*)&k_s [j * 64 + gg];
        bk2[ni] = *(const bf16x8*)&k2_s[j * 64 + gg];
      }
      #pragma unroll
      for (int ni = 0; ni < 4; ++ni) {
        a1[ni] = MFMA(fq [ks], bk [ni], a1[ni]);
        a2[ni] = MFMA(fq2[ks], bk2[ni], a2[ni]);
      }
    }

    // normalize + gate + causal mask, tile row-max (wave-local)
    float tmax[4];
    #pragma unroll
    for (int e = 0; e < 4; ++e) tmax[e] = -INFINITY;
    #pragma unroll
    for (int ni = 0; ni < 4; ++ni)
      #pragma unroll
      for (int e = 0; e < 4; ++e) {
        int gr = m0 + w * 16 + l4 * 4 + e;
        int gc = t0 + ni * 16 + l15;
        float n1 = (a1[ni][e] - mu1[e]) * iv1[e];
        float n2 = (a2[ni][e] - mu2[e]) * iv2[e];
        float s  = n1 * (om + mq * n2);
        s = (gc <= gr) ? s : -INFINITY;
        a1[ni][e] = s;
        tmax[e] = fmaxf(tmax[e], s);
      }
    #pragma unroll
    for (int o = 1; o <= 8; o <<= 1)
      #pragma unroll
      for (int e = 0; e < 4; ++e)
        tmax[e] = fmaxf(tmax[e], __shfl_xor(tmax[e], o));

    float fac[4];
    #pragma unroll
    for (int e = 0; e < 4; ++e) {
      float mn = fmaxf(mrow[e], tmax[e]);
      fac[e] = __expf(mrow[e] - mn);             // 0 on first tile
      mrow[e] = mn;
      lrow[e] *= fac[e];
    }

    // P = exp(s-m), wave-local row-sum, write P to own p_s rows
    float tsum[4] = {};
    #pragma unroll
    for (int ni = 0; ni < 4; ++ni)
      #pragma unroll
      for (int e = 0; e < 4; ++e) {
        float s = a1[ni][e];
        float p = (s > -INFINITY) ? __expf(s - mrow[e]) : 0.f;
        tsum[e] += p;
        p_s[(w * 16 + l4 * 4 + e) * 68 + ni * 16 + l15] = f2bf(p);
      }
    #pragma unroll
    for (int o = 1; o <= 8; o <<= 1)
      #pragma unroll
      for (int e = 0; e < 4; ++e)
        tsum[e] += __shfl_xor(tsum[e], o);
    #pragma unroll
    for (int e = 0; e < 4; ++e) lrow[e] += tsum[e];
    #pragma unroll
    for (int ni = 0; ni < 4; ++ni)
      #pragma unroll
      for (int e = 0; e < 4; ++e)
        accO[ni][e] *= fac[e];

    // PV: wave-local P rows (no barrier needed; compiler orders ds ops)
    #pragma unroll
    for (int ks = 0; ks < 2; ++ks) {
      int po = (w * 16 + l15) * 68 + ks * 32 + l4 * 8;
      bf16x4 plo = *(const bf16x4*)&p_s[po];
      bf16x4 phi = *(const bf16x4*)&p_s[po + 4];
      bf16x8 ap = __builtin_shufflevector(plo, phi, 0, 1, 2, 3, 4, 5, 6, 7);
      bf16x8 bv[4];
      #pragma unroll
      for (int ni = 0; ni < 4; ++ni) {
        int d  = ni * 16 + l15;
        int gg = ((ks * 4 + l4) ^ (d & 7)) * 8;
        bv[ni] = *(const bf16x8*)&v_s[d * 64 + gg];
      }
      #pragma unroll
      for (int ni = 0; ni < 4; ++ni)
        accO[ni] = MFMA(ap, bv[ni], accO[ni]);
    }
  }

  // ---- epilogue: O / l -> yb ----
  float invl[4];
  #pragma unroll
  for (int e = 0; e < 4; ++e) invl[e] = 1.f / lrow[e];
  #pragma unroll
  for (int ni = 0; ni < 4; ++ni)
    #pragma unroll
    for (int e = 0; e < 4; ++e)
      Y[(size_t)(m0 + w * 16 + l4 * 4 + e) * CS + ni * 16 + l15] =
          f2bf(accO[ni][e] * invl[e]);
}

// ---------------- launcher ----------------
extern "C" void kernel_launch(void* const* d_in, const int* in_sizes, int n_in,
                              void* d_out, int out_size, void* d_ws, size_t ws_size,
                              hipStream_t stream) {
  const float* x    = (const float*)d_in[0];
  const float* Wq   = (const float*)d_in[1];
  const float* Wk   = (const float*)d_in[2];
  const float* Wv   = (const float*)d_in[3];
  const float* Wq2  = (const float*)d_in[4];
  const float* Wk2  = (const float*)d_in[5];
  const float* Wo   = (const float*)d_in[6];
  const float* mixture = (const float*)d_in[7];
  const float* qsc  = (const float*)d_in[8];
  float* out = (float*)d_out;

  const size_t MT = (size_t)NBATCH * TS;   // 2048
  ushort* ws = (ushort*)d_ws;
  ushort* xb   = ws;                                  // 2M
  ushort* wcat = xb   + (size_t)2 * MEG;              // 6M: wq,wk,wq2,wk2,wv,wo
  ushort* qb   = wcat + (size_t)6 * MEG;              // 2M (pre-scaled by 1/8)
  ushort* q2b  = qb   + (size_t)2 * MEG;              // 2M (pre-scaled by 1/8)
  ushort* kb   = q2b  + (size_t)2 * MEG;              // 2M
  ushort* k2b  = kb   + (size_t)2 * MEG;              // 2M
  ushort* vtb  = k2b  + (size_t)2 * MEG;              // 2M  [B*NH][64][T]
  ushort* yb   = vtb  + (size_t)2 * MEG;              // 2M
  ushort* ktb  = yb   + (size_t)2 * MEG;              // 2M  [B*NH][64][T]
  ushort* k2tb = ktb  + (size_t)2 * MEG;              // 2M
  ushort* g1b  = k2tb + (size_t)2 * MEG;              // 128K: [32][64][64] bf16
  ushort* g2b  = g1b  + (size_t)(MEG / 8);            // 128K
  float*  csb  = (float*)(g2b + (size_t)(MEG / 8));   // [2][32][64] fp32
  ushort* wob  = wcat + (size_t)5 * MEG;

  // 1. cast everything to bf16
  cast_all<<<2048, 256, 0, stream>>>(x, Wq, Wk, Wv, Wq2, Wk2, Wo, xb, wcat);

  // 2. fused projections (+ transposed K, K2 for gram)
  gemm_proj<<<dim3(5 * CS / BN, MT / BM, 1), 256, 0, stream>>>(
      xb, wcat, qb, kb, q2b, k2b, vtb, ktb, k2tb);

  // 3. Gram matrices + colsums (row-stat shortcut: sum s = q.cs ; sum s^2 = q^T G q)
  gram<<<64, 256, 0, stream>>>(ktb, k2tb, g1b, g2b, csb);

  // 4. fused attention
  attn_fused<<<512, 256, 0, stream>>>(qb, kb, q2b, k2b, vtb, yb,
                                      g1b, g2b, csb, mixture, qsc);

  // 5. output projection (fp32 out)
  gemm_bt<1><<<dim3(CS / BN, MT / BM, 1), 256, 0, stream>>>(
      yb, wob, out, (int)MT, CS, CS, CS, CS, CS, 0, 0, 0, 0, 0, 0, 1.f);
}

// Round 5
// 121.858 us; speedup vs baseline: 1.2635x; 1.2635x over previous
//
#include <hip/hip_runtime.h>
#include <hip/hip_bf16.h>
#include <stdint.h>

#define TS 1024   // T
#define CS 1024   // C
#define NH 16
#define DHEAD 64
#define NBATCH 2
#define EPSV 1e-5f
#define MEG 1048576

typedef __bf16 bf16x8 __attribute__((ext_vector_type(8)));
typedef __bf16 bf16x4 __attribute__((ext_vector_type(4)));
typedef float  f32x4  __attribute__((ext_vector_type(4)));

#define MFMA(a, b, c) __builtin_amdgcn_mfma_f32_16x16x32_bf16((a), (b), (c), 0, 0, 0)

__device__ __forceinline__ float bf2f(ushort u){
  union { uint32_t i; float f; } v; v.i = ((uint32_t)u) << 16; return v.f;
}
__device__ __forceinline__ ushort f2bf(float f){
  union { float f; uint32_t i; } v; v.f = f;
  uint32_t r = v.i + 0x7FFFu + ((v.i >> 16) & 1u);
  return (ushort)(r >> 16);
}

// async global->LDS, 16B per lane. LDS dest wave-uniform base + lane*16B (linear);
// global src per-lane (enables pre-swizzled-source LDS layouts).
__device__ __forceinline__ void gl_lds16(const ushort* g, ushort* l) {
  __builtin_amdgcn_global_load_lds(
      (const __attribute__((address_space(1))) void*)g,
      (__attribute__((address_space(3))) void*)l, 16, 0, 0);
}

// ---------------- fused cast fp32 -> bf16 of all 7 tensors ----------------
__global__ __launch_bounds__(256)
void cast_all(const float* __restrict__ x,
              const float* __restrict__ Wq, const float* __restrict__ Wk,
              const float* __restrict__ Wv, const float* __restrict__ Wq2,
              const float* __restrict__ Wk2, const float* __restrict__ Wo,
              ushort* __restrict__ xb, ushort* __restrict__ wcat)
{
  const int XC = 524288, TOT = 2097152;
  for (int idx = blockIdx.x * 256 + threadIdx.x; idx < TOT; idx += 524288) {
    const float* s; ushort* d; int c;
    if (idx < XC) { s = x; d = xb; c = idx; }
    else {
      int r = idx - XC; int w = r >> 18; c = r & 262143;
      switch (w) {
        case 0:  s = Wq;  d = wcat;           break;
        case 1:  s = Wk;  d = wcat + 1*MEG;   break;
        case 2:  s = Wv;  d = wcat + 4*MEG;   break;
        case 3:  s = Wq2; d = wcat + 2*MEG;   break;
        case 4:  s = Wk2; d = wcat + 3*MEG;   break;
        default: s = Wo;  d = wcat + 5*MEG;   break;
      }
    }
    float4 v = *(const float4*)(s + (size_t)c * 4);
    ushort4 o; o.x = f2bf(v.x); o.y = f2bf(v.y); o.z = f2bf(v.z); o.w = f2bf(v.w);
    *(ushort4*)(d + (size_t)c * 4) = o;
  }
}

// ---------------- generic bf16 B^T GEMM (global_load_lds staging) ----------------
#define BM 128
#define BN 128
#define BKK 32

template<int EPI>
__global__ __launch_bounds__(256, 2)
void gemm_bt(const ushort* __restrict__ A, const ushort* __restrict__ Bt,
             void* __restrict__ Cout,
             int M, int N, int K, int lda, int ldb, int ldc,
             long sA1, long sA2, long sB1, long sB2, long sC1, long sC2,
             float scale)
{
  __shared__ ushort a_s[BM * BKK];
  __shared__ ushort b_s[BN * BKK];

  const int z = blockIdx.z, zh = z >> 4, zl = z & 15;
  A  += (size_t)zh * sA1 + (size_t)zl * sA2;
  Bt += (size_t)zh * sB1 + (size_t)zl * sB2;

  const int n0 = blockIdx.x * BN;
  const int m0 = blockIdx.y * BM;

  const int t  = threadIdx.x;
  const int w  = t >> 6, l = t & 63;
  const int wr = w >> 1, wc = w & 1;
  const int l15 = l & 15, l4 = l >> 4;

  const int rs = l >> 2;
  const int c8 = (l & 3) * 8;

  f32x4 acc[4][4] = {};

  for (int k0 = 0; k0 < K; k0 += BKK) {
    #pragma unroll
    for (int j = 0; j < 2; ++j) {
      int ch = w * 2 + j;
      int r  = ch * 16 + rs;
      gl_lds16(&A [(size_t)(m0 + r) * lda + k0 + c8], &a_s[ch * 512]);
      gl_lds16(&Bt[(size_t)(n0 + r) * ldb + k0 + c8], &b_s[ch * 512]);
    }
    __syncthreads();

    bf16x8 af[4], bfr[4];
    #pragma unroll
    for (int mi = 0; mi < 4; ++mi)
      af[mi] = *(const bf16x8*)&a_s[(wr * 64 + mi * 16 + l15) * BKK + l4 * 8];
    #pragma unroll
    for (int ni = 0; ni < 4; ++ni)
      bfr[ni] = *(const bf16x8*)&b_s[(wc * 64 + ni * 16 + l15) * BKK + l4 * 8];

    #pragma unroll
    for (int mi = 0; mi < 4; ++mi)
      #pragma unroll
      for (int ni = 0; ni < 4; ++ni)
        acc[mi][ni] = MFMA(af[mi], bfr[ni], acc[mi][ni]);

    __syncthreads();
  }

  #pragma unroll
  for (int mi = 0; mi < 4; ++mi) {
    #pragma unroll
    for (int ni = 0; ni < 4; ++ni) {
      int col  = n0 + wc * 64 + ni * 16 + l15;
      int row0 = m0 + wr * 64 + mi * 16 + l4 * 4;
      if (EPI == 0) {
        ushort* C = (ushort*)Cout + (size_t)zh * sC1 + (size_t)zl * sC2;
        #pragma unroll
        for (int e = 0; e < 4; ++e)
          C[(size_t)(row0 + e) * ldc + col] = f2bf(acc[mi][ni][e] * scale);
      } else {
        float* C = (float*)Cout + (size_t)zh * sC1 + (size_t)zl * sC2;
        #pragma unroll
        for (int e = 0; e < 4; ++e)
          C[(size_t)(row0 + e) * ldc + col] = acc[mi][ni][e] * scale;
      }
    }
  }
}

// ---------------- fused projection GEMM: [x]@[Wq;Wk;Wq2;Wk2;Wv]^T ----------------
// seg 0..3 -> q/k/q2/k2 row-major (q,q2 pre-scaled by 1/8, exact in bf16);
// seg 1,3 additionally write transposed K/K2 ([z][64][T], like V) for the gram kernel;
// seg 4 -> V transposed per head.
__global__ __launch_bounds__(256, 2)
void gemm_proj(const ushort* __restrict__ A, const ushort* __restrict__ Bt,
               ushort* __restrict__ qb, ushort* __restrict__ kb,
               ushort* __restrict__ q2b, ushort* __restrict__ k2b,
               ushort* __restrict__ vtb,
               ushort* __restrict__ ktb, ushort* __restrict__ k2tb)
{
  __shared__ ushort a_s[BM * BKK];
  __shared__ ushort b_s[BN * BKK];

  const int n0 = blockIdx.x * BN;
  const int m0 = blockIdx.y * BM;

  const int t  = threadIdx.x;
  const int w  = t >> 6, l = t & 63;
  const int wr = w >> 1, wc = w & 1;
  const int l15 = l & 15, l4 = l >> 4;

  const int rs = l >> 2;
  const int c8 = (l & 3) * 8;

  f32x4 acc[4][4] = {};

  for (int k0 = 0; k0 < CS; k0 += BKK) {
    #pragma unroll
    for (int j = 0; j < 2; ++j) {
      int ch = w * 2 + j;
      int r  = ch * 16 + rs;
      gl_lds16(&A [(size_t)(m0 + r) * CS + k0 + c8], &a_s[ch * 512]);
      gl_lds16(&Bt[(size_t)(n0 + r) * CS + k0 + c8], &b_s[ch * 512]);
    }
    __syncthreads();

    bf16x8 af[4], bfr[4];
    #pragma unroll
    for (int mi = 0; mi < 4; ++mi)
      af[mi] = *(const bf16x8*)&a_s[(wr * 64 + mi * 16 + l15) * BKK + l4 * 8];
    #pragma unroll
    for (int ni = 0; ni < 4; ++ni)
      bfr[ni] = *(const bf16x8*)&b_s[(wc * 64 + ni * 16 + l15) * BKK + l4 * 8];

    #pragma unroll
    for (int mi = 0; mi < 4; ++mi)
      #pragma unroll
      for (int ni = 0; ni < 4; ++ni)
        acc[mi][ni] = MFMA(af[mi], bfr[ni], acc[mi][ni]);

    __syncthreads();
  }

  #pragma unroll
  for (int mi = 0; mi < 4; ++mi) {
    #pragma unroll
    for (int ni = 0; ni < 4; ++ni) {
      int col  = n0 + wc * 64 + ni * 16 + l15;
      int row0 = m0 + wr * 64 + mi * 16 + l4 * 4;
      int seg  = col >> 10, cc = col & (CS - 1);
      if (seg < 4) {
        ushort* dst = (seg == 0) ? qb : (seg == 1) ? kb : (seg == 2) ? q2b : k2b;
        float sc = (seg & 1) ? 1.f : 0.125f;   // fold 1/sqrt(Dh) into q, q2
        #pragma unroll
        for (int e = 0; e < 4; ++e)
          dst[(size_t)(row0 + e) * CS + cc] = f2bf(acc[mi][ni][e] * sc);
        if (seg == 1 || seg == 3) {
          int bb = row0 >> 10, tt = row0 & (TS - 1);
          int hh = cc >> 6, dd = cc & (DHEAD - 1);
          ushort* td = (seg == 1) ? ktb : k2tb;
          ushort4 o;
          o.x = f2bf(acc[mi][ni][0]); o.y = f2bf(acc[mi][ni][1]);
          o.z = f2bf(acc[mi][ni][2]); o.w = f2bf(acc[mi][ni][3]);
          *(ushort4*)&td[(((size_t)(bb * NH + hh) * DHEAD + dd) * TS) + tt] = o;
        }
      } else {
        int bb = row0 >> 10, tt = row0 & (TS - 1);
        int hh = cc >> 6, dd = cc & (DHEAD - 1);
        ushort4 o;
        o.x = f2bf(acc[mi][ni][0]); o.y = f2bf(acc[mi][ni][1]);
        o.z = f2bf(acc[mi][ni][2]); o.w = f2bf(acc[mi][ni][3]);
        *(ushort4*)&vtb[(((size_t)(bb * NH + hh) * DHEAD + dd) * TS) + tt] = o;
      }
    }
  }
}

// ---------------- Gram kernel: G = K^T K (64x64, bf16 out) + colsum(K) ----------
// grid = 64: blockIdx.x = z*2 + mat. Reads transposed K layout [z][64 d][T].
__global__ __launch_bounds__(256, 2)
void gram(const ushort* __restrict__ ktb, const ushort* __restrict__ k2tb,
          ushort* __restrict__ g1b, ushort* __restrict__ g2b,
          float* __restrict__ csb)
{
  __shared__ ushort t_s[64 * 128];   // [64 d][128 t], granule-swizzled g ^= d&15

  const int mat = blockIdx.x & 1, z = blockIdx.x >> 1;
  const ushort* S = (mat ? k2tb : ktb) + (size_t)z * DHEAD * TS;

  const int t = threadIdx.x, w = t >> 6, l = t & 63;
  const int l15 = l & 15, l4 = l >> 4;

  f32x4 acc[4] = {};
  float csacc = 0.f;

  for (int tt = 0; tt < 8; ++tt) {
    const int t0 = tt * 128;
    __syncthreads();
    #pragma unroll
    for (int i = 0; i < 4; ++i) {
      int issue = w * 4 + i;
      int row = issue * 4 + l4;
      int gs  = l15 ^ (row & 15);
      gl_lds16(&S[(size_t)row * TS + t0 + gs * 8], &t_s[issue * 512]);
    }
    __syncthreads();

    // colsum partial: lane handles row w*16+l15, t-granules l4*4..+3
    {
      int r = w * 16 + l15;
      #pragma unroll
      for (int j = 0; j < 4; ++j) {
        int gg = ((l4 * 4 + j) ^ (r & 15)) * 8;
        uint4 vv = *(const uint4*)&t_s[r * 128 + gg];
        const ushort* pu = (const ushort*)&vv;
        #pragma unroll
        for (int e2 = 0; e2 < 8; ++e2) csacc += bf2f(pu[e2]);
      }
    }

    #pragma unroll
    for (int ks = 0; ks < 4; ++ks) {
      int ar = w * 16 + l15;
      bf16x8 af = *(const bf16x8*)&t_s[ar * 128 + ((ks * 4 + l4) ^ (ar & 15)) * 8];
      #pragma unroll
      for (int ni = 0; ni < 4; ++ni) {
        int br = ni * 16 + l15;
        bf16x8 bf_ = *(const bf16x8*)&t_s[br * 128 + ((ks * 4 + l4) ^ (br & 15)) * 8];
        acc[ni] = MFMA(af, bf_, acc[ni]);
      }
    }
  }

  csacc += __shfl_xor(csacc, 16);
  csacc += __shfl_xor(csacc, 32);
  if (l4 == 0)
    csb[(mat * 32 + z) * 64 + w * 16 + l15] = csacc;

  ushort* G = (mat ? g2b : g1b) + (size_t)z * 4096;
  #pragma unroll
  for (int ni = 0; ni < 4; ++ni)
    #pragma unroll
    for (int e = 0; e < 4; ++e)
      G[(w * 16 + l4 * 4 + e) * 64 + ni * 16 + l15] = f2bf(acc[ni][e]);
}

// ---------------- fused attention v3: 2-phase prefetch pipeline ----------------
// Block: one head z, one 64-row Q-tile. 4 waves; wave w owns rows [w*16, w*16+16).
// Stats via Gram trick. K/K2/V double-buffered; per iter: issue stage(t+1) ->
// compute(t) -> ONE barrier (vmcnt drain lands after compute => HBM latency hidden).
__global__ __launch_bounds__(256, 2)
void attn_fused(const ushort* __restrict__ qb, const ushort* __restrict__ kb,
                const ushort* __restrict__ q2b, const ushort* __restrict__ k2b,
                const ushort* __restrict__ vtb, ushort* __restrict__ yb,
                const ushort* __restrict__ g1b, const ushort* __restrict__ g2b,
                const float* __restrict__ csb,
                const float* __restrict__ mixture, const float* __restrict__ qsc)
{
  __shared__ ushort kbuf [2][4096];  // K tile  [64 t][64 d] swz g^=t&7  (buf0: Q in phase A)
  __shared__ ushort k2buf[2][4096];  // K2 tile                          (buf0: Q2 in phase A)
  __shared__ ushort vbuf [2][4096];  // V tile  [64 d][64 t] swz g^=d&7  (buf0: G1 in phase A)
  __shared__ ushort p_s  [64 * 68];  // P tile [64 r][64+4 pad]          (G2 in phase A)

  const int idx  = blockIdx.x;
  const int xcd  = idx & 7, slot = idx >> 3;
  const int z    = ((slot >> 4) << 3) + xcd;     // head id 0..31, affine to XCD
  const int s4   = slot & 15;                    // big/small interleave: 15,0,14,1,...
  const int qt   = (s4 & 1) ? (s4 >> 1) : (15 - (s4 >> 1));
  const int b    = z >> 4, h = z & 15;
  const int m0   = qt * 64;

  const ushort* Q  = qb  + (size_t)b * TS * CS + h * DHEAD;
  const ushort* Q2 = q2b + (size_t)b * TS * CS + h * DHEAD;
  const ushort* K  = kb  + (size_t)b * TS * CS + h * DHEAD;
  const ushort* K2 = k2b + (size_t)b * TS * CS + h * DHEAD;
  const ushort* Vt = vtb + (size_t)z * DHEAD * TS;
  const ushort* G1 = g1b + (size_t)z * 4096;
  const ushort* G2 = g2b + (size_t)z * 4096;
  ushort* Y = yb + (size_t)b * TS * CS + h * DHEAD;

  const int t = threadIdx.x, w = t >> 6, l = t & 63;
  const int l15 = l & 15, l4 = l >> 4;
  const int r8 = l >> 3, g7 = l & 7;

  const float gm = 1.f / (1.f + __expf(-mixture[0]));
  const float mq = gm * qsc[0];
  const float om = 1.f - gm;

  auto stage_tile = [&](int ct, int bs) {
    const int t0 = ct * 64;
    #pragma unroll
    for (int i = 0; i < 2; ++i) {
      int issue = w * 2 + i;
      int row = issue * 8 + r8;
      int gs  = g7 ^ (row & 7);
      gl_lds16(&K [(size_t)(t0 + row) * CS + gs * 8], &kbuf [bs][issue * 512]);
      gl_lds16(&K2[(size_t)(t0 + row) * CS + gs * 8], &k2buf[bs][issue * 512]);
      gl_lds16(&Vt[(size_t)row * TS + t0 + gs * 8], &vbuf[bs][issue * 512]);
    }
  };

  // ---- phase A: stage Q,Q2,G1 -> buf0, G2 -> p_s ; AND tile0 -> buf1 ----
  #pragma unroll
  for (int i = 0; i < 2; ++i) {
    int issue = w * 2 + i;
    int row = issue * 8 + r8;
    int gs  = g7 ^ (row & 7);
    gl_lds16(&Q [(size_t)(m0 + row) * CS + gs * 8], &kbuf [0][issue * 512]);
    gl_lds16(&Q2[(size_t)(m0 + row) * CS + gs * 8], &k2buf[0][issue * 512]);
    gl_lds16(&G1[row * 64 + gs * 8], &vbuf[0][issue * 512]);
    gl_lds16(&G2[row * 64 + gs * 8], &p_s[issue * 512]);
  }
  stage_tile(0, 1);
  __syncthreads();                   // single drain for Q/G + tile0

  // Q fragments (A-frag: row w*16+l15, k-slice ks*32+l4*8)
  const int qrow = w * 16 + l15;
  bf16x8 fq[2], fq2[2];
  #pragma unroll
  for (int ks = 0; ks < 2; ++ks) {
    int gg = ((ks * 4 + l4) ^ (qrow & 7)) * 8;
    fq [ks] = *(const bf16x8*)&kbuf [0][qrow * 64 + gg];
    fq2[ks] = *(const bf16x8*)&k2buf[0][qrow * 64 + gg];
  }

  // U = Q @ G (G symmetric; B-frag rows = G rows)
  f32x4 U1[4] = {}, U2[4] = {};
  #pragma unroll
  for (int ks = 0; ks < 2; ++ks) {
    #pragma unroll
    for (int ni = 0; ni < 4; ++ni) {
      int gr = ni * 16 + l15;
      int gg = ((ks * 4 + l4) ^ (gr & 7)) * 8;
      bf16x8 bg1 = *(const bf16x8*)&vbuf[0][gr * 64 + gg];
      bf16x8 bg2 = *(const bf16x8*)&p_s[gr * 64 + gg];
      U1[ni] = MFMA(fq [ks], bg1, U1[ni]);
      U2[ni] = MFMA(fq2[ks], bg2, U2[ni]);
    }
  }

  float cs1[4], cs2[4];
  #pragma unroll
  for (int ni = 0; ni < 4; ++ni) {
    cs1[ni] = csb[z * 64 + ni * 16 + l15];
    cs2[ni] = csb[2048 + z * 64 + ni * 16 + l15];
  }

  // per-row stats: sumsq = sum_d U[r][d]*q[r][d] ; mudot = sum_d q[r][d]*cs[d]
  float mu1[4], iv1[4], mu2[4], iv2[4];
  #pragma unroll
  for (int e = 0; e < 4; ++e) {
    int rl = w * 16 + l4 * 4 + e;
    float ssq1 = 0.f, md1 = 0.f, ssq2 = 0.f, md2 = 0.f;
    #pragma unroll
    for (int ni = 0; ni < 4; ++ni) {
      int d  = ni * 16 + l15;
      int ad = rl * 64 + (((d >> 3) ^ (rl & 7)) << 3) + (d & 7);
      float qv1 = bf2f(kbuf [0][ad]);
      float qv2 = bf2f(k2buf[0][ad]);
      ssq1 = fmaf(U1[ni][e], qv1, ssq1); md1 = fmaf(qv1, cs1[ni], md1);
      ssq2 = fmaf(U2[ni][e], qv2, ssq2); md2 = fmaf(qv2, cs2[ni], md2);
    }
    #pragma unroll
    for (int o = 1; o <= 8; o <<= 1) {
      ssq1 += __shfl_xor(ssq1, o); md1 += __shfl_xor(md1, o);
      ssq2 += __shfl_xor(ssq2, o); md2 += __shfl_xor(md2, o);
    }
    float m1 = md1 * (1.f / TS), m2 = md2 * (1.f / TS);
    float v1 = (ssq1 - (float)TS * m1 * m1) * (1.f / (TS - 1));
    float v2 = (ssq2 - (float)TS * m2 * m2) * (1.f / (TS - 1));
    mu1[e] = m1; iv1[e] = 1.f / (sqrtf(fmaxf(v1, 0.f)) + EPSV);
    mu2[e] = m2; iv2[e] = 1.f / (sqrtf(fmaxf(v2, 0.f)) + EPSV);
  }
  __syncthreads();                   // all waves done reading buf0 / p_s(G2)

  // ---- tile loop: prefetch(t+1) -> compute(t) -> barrier ----
  float mrow[4], lrow[4];
  #pragma unroll
  for (int e = 0; e < 4; ++e) { mrow[e] = -INFINITY; lrow[e] = 0.f; }
  f32x4 accO[4] = {};

  for (int ct = 0; ct <= qt; ++ct) {
    const int t0  = ct * 64;
    const int cur = (ct & 1) ^ 1;    // tile0 in buf1, tile1 in buf0, ...
    if (ct < qt) stage_tile(ct + 1, cur ^ 1);

    const ushort* ks_ = kbuf [cur];
    const ushort* k2s_= k2buf[cur];
    const ushort* vs_ = vbuf [cur];

    // QK^T for both matrices (wave rows x 64 cols)
    f32x4 a1[4] = {}, a2[4] = {};
    #pragma unroll
    for (int ks = 0; ks < 2; ++ks) {
      bf16x8 bk[4], bk2[4];
      #pragma unroll
      for (int ni = 0; ni < 4; ++ni) {
        int j  = ni * 16 + l15;
        int gg = ((ks * 4 + l4) ^ (j & 7)) * 8;
        bk [ni] = *(const bf16x8*)&ks_ [j * 64 + gg];
        bk2[ni] = *(const bf16x8*)&k2s_[j * 64 + gg];
      }
      #pragma unroll
      for (int ni = 0; ni < 4; ++ni) {
        a1[ni] = MFMA(fq [ks], bk [ni], a1[ni]);
        a2[ni] = MFMA(fq2[ks], bk2[ni], a2[ni]);
      }
    }

    // normalize + gate + causal mask, tile row-max (wave-local)
    float tmax[4];
    #pragma unroll
    for (int e = 0; e < 4; ++e) tmax[e] = -INFINITY;
    #pragma unroll
    for (int ni = 0; ni < 4; ++ni)
      #pragma unroll
      for (int e = 0; e < 4; ++e) {
        int gr = m0 + w * 16 + l4 * 4 + e;
        int gc = t0 + ni * 16 + l15;
        float n1 = (a1[ni][e] - mu1[e]) * iv1[e];
        float n2 = (a2[ni][e] - mu2[e]) * iv2[e];
        float s  = n1 * (om + mq * n2);
        s = (gc <= gr) ? s : -INFINITY;
        a1[ni][e] = s;
        tmax[e] = fmaxf(tmax[e], s);
      }
    #pragma unroll
    for (int o = 1; o <= 8; o <<= 1)
      #pragma unroll
      for (int e = 0; e < 4; ++e)
        tmax[e] = fmaxf(tmax[e], __shfl_xor(tmax[e], o));

    float fac[4];
    #pragma unroll
    for (int e = 0; e < 4; ++e) {
      float mn = fmaxf(mrow[e], tmax[e]);
      fac[e] = __expf(mrow[e] - mn);             // 0 on first tile
      mrow[e] = mn;
      lrow[e] *= fac[e];
    }

    // P = exp(s-m), wave-local row-sum, write P to own p_s rows
    float tsum[4] = {};
    #pragma unroll
    for (int ni = 0; ni < 4; ++ni)
      #pragma unroll
      for (int e = 0; e < 4; ++e) {
        float s = a1[ni][e];
        float p = (s > -INFINITY) ? __expf(s - mrow[e]) : 0.f;
        tsum[e] += p;
        p_s[(w * 16 + l4 * 4 + e) * 68 + ni * 16 + l15] = f2bf(p);
      }
    #pragma unroll
    for (int o = 1; o <= 8; o <<= 1)
      #pragma unroll
      for (int e = 0; e < 4; ++e)
        tsum[e] += __shfl_xor(tsum[e], o);
    #pragma unroll
    for (int e = 0; e < 4; ++e) lrow[e] += tsum[e];
    #pragma unroll
    for (int ni = 0; ni < 4; ++ni)
      #pragma unroll
      for (int e = 0; e < 4; ++e)
        accO[ni][e] *= fac[e];

    // PV: wave-local P rows (same-wave lgkmcnt ordering; no barrier)
    #pragma unroll
    for (int ks = 0; ks < 2; ++ks) {
      int po = (w * 16 + l15) * 68 + ks * 32 + l4 * 8;
      bf16x4 plo = *(const bf16x4*)&p_s[po];
      bf16x4 phi = *(const bf16x4*)&p_s[po + 4];
      bf16x8 ap = __builtin_shufflevector(plo, phi, 0, 1, 2, 3, 4, 5, 6, 7);
      bf16x8 bv[4];
      #pragma unroll
      for (int ni = 0; ni < 4; ++ni) {
        int d  = ni * 16 + l15;
        int gg = ((ks * 4 + l4) ^ (d & 7)) * 8;
        bv[ni] = *(const bf16x8*)&vs_[d * 64 + gg];
      }
      #pragma unroll
      for (int ni = 0; ni < 4; ++ni)
        accO[ni] = MFMA(ap, bv[ni], accO[ni]);
    }

    __syncthreads();   // drains prefetch (issued pre-compute) + releases cur
  }

  // ---- epilogue: O / l -> yb ----
  float invl[4];
  #pragma unroll
  for (int e = 0; e < 4; ++e) invl[e] = 1.f / lrow[e];
  #pragma unroll
  for (int ni = 0; ni < 4; ++ni)
    #pragma unroll
    for (int e = 0; e < 4; ++e)
      Y[(size_t)(m0 + w * 16 + l4 * 4 + e) * CS + ni * 16 + l15] =
          f2bf(accO[ni][e] * invl[e]);
}

// ---------------- launcher ----------------
extern "C" void kernel_launch(void* const* d_in, const int* in_sizes, int n_in,
                              void* d_out, int out_size, void* d_ws, size_t ws_size,
                              hipStream_t stream) {
  const float* x    = (const float*)d_in[0];
  const float* Wq   = (const float*)d_in[1];
  const float* Wk   = (const float*)d_in[2];
  const float* Wv   = (const float*)d_in[3];
  const float* Wq2  = (const float*)d_in[4];
  const float* Wk2  = (const float*)d_in[5];
  const float* Wo   = (const float*)d_in[6];
  const float* mixture = (const float*)d_in[7];
  const float* qsc  = (const float*)d_in[8];
  float* out = (float*)d_out;

  const size_t MT = (size_t)NBATCH * TS;   // 2048
  ushort* ws = (ushort*)d_ws;
  ushort* xb   = ws;                                  // 2M
  ushort* wcat = xb   + (size_t)2 * MEG;              // 6M: wq,wk,wq2,wk2,wv,wo
  ushort* qb   = wcat + (size_t)6 * MEG;              // 2M (pre-scaled by 1/8)
  ushort* q2b  = qb   + (size_t)2 * MEG;              // 2M (pre-scaled by 1/8)
  ushort* kb   = q2b  + (size_t)2 * MEG;              // 2M
  ushort* k2b  = kb   + (size_t)2 * MEG;              // 2M
  ushort* vtb  = k2b  + (size_t)2 * MEG;              // 2M  [B*NH][64][T]
  ushort* yb   = vtb  + (size_t)2 * MEG;              // 2M
  ushort* ktb  = yb   + (size_t)2 * MEG;              // 2M  [B*NH][64][T]
  ushort* k2tb = ktb  + (size_t)2 * MEG;              // 2M
  ushort* g1b  = k2tb + (size_t)2 * MEG;              // 128K: [32][64][64] bf16
  ushort* g2b  = g1b  + (size_t)(MEG / 8);            // 128K
  float*  csb  = (float*)(g2b + (size_t)(MEG / 8));   // [2][32][64] fp32
  ushort* wob  = wcat + (size_t)5 * MEG;

  // 1. cast everything to bf16
  cast_all<<<2048, 256, 0, stream>>>(x, Wq, Wk, Wv, Wq2, Wk2, Wo, xb, wcat);

  // 2. fused projections (+ transposed K, K2 for gram)
  gemm_proj<<<dim3(5 * CS / BN, MT / BM, 1), 256, 0, stream>>>(
      xb, wcat, qb, kb, q2b, k2b, vtb, ktb, k2tb);

  // 3. Gram matrices + colsums (row-stat shortcut: sum s = q.cs ; sum s^2 = q^T G q)
  gram<<<64, 256, 0, stream>>>(ktb, k2tb, g1b, g2b, csb);

  // 4. fused attention (2-phase prefetch)
  attn_fused<<<512, 256, 0, stream>>>(qb, kb, q2b, k2b, vtb, yb,
                                      g1b, g2b, csb, mixture, qsc);

  // 5. output projection (fp32 out)
  gemm_bt<1><<<dim3(CS / BN, MT / BM, 1), 256, 0, stream>>>(
      yb, wob, out, (int)MT, CS, CS, CS, CS, CS, 0, 0, 0, 0, 0, 0, 1.f);
}

// Round 6
// 105.076 us; speedup vs baseline: 1.4653x; 1.1597x over previous
//
#include <hip/hip_runtime.h>
#include <hip/hip_bf16.h>
#include <stdint.h>

#define TS 1024   // T
#define CS 1024   // C
#define NH 16
#define DHEAD 64
#define NBATCH 2
#define EPSV 1e-5f
#define MEG 1048576

typedef __bf16 bf16x8 __attribute__((ext_vector_type(8)));
typedef __bf16 bf16x4 __attribute__((ext_vector_type(4)));
typedef float  f32x4  __attribute__((ext_vector_type(4)));

#define MFMA(a, b, c) __builtin_amdgcn_mfma_f32_16x16x32_bf16((a), (b), (c), 0, 0, 0)

__device__ __forceinline__ float bf2f(ushort u){
  union { uint32_t i; float f; } v; v.i = ((uint32_t)u) << 16; return v.f;
}
__device__ __forceinline__ ushort f2bf(float f){
  union { float f; uint32_t i; } v; v.f = f;
  uint32_t r = v.i + 0x7FFFu + ((v.i >> 16) & 1u);
  return (ushort)(r >> 16);
}

// async global->LDS, 16B per lane. LDS dest wave-uniform base + lane*16B (linear);
// global src per-lane (enables pre-swizzled-source LDS layouts).
__device__ __forceinline__ void gl_lds16(const ushort* g, ushort* l) {
  __builtin_amdgcn_global_load_lds(
      (const __attribute__((address_space(1))) void*)g,
      (__attribute__((address_space(3))) void*)l, 16, 0, 0);
}

// ---------------- fused cast fp32 -> bf16 of all 7 tensors ----------------
__global__ __launch_bounds__(256)
void cast_all(const float* __restrict__ x,
              const float* __restrict__ Wq, const float* __restrict__ Wk,
              const float* __restrict__ Wv, const float* __restrict__ Wq2,
              const float* __restrict__ Wk2, const float* __restrict__ Wo,
              ushort* __restrict__ xb, ushort* __restrict__ wcat)
{
  const int XC = 524288, TOT = 2097152;
  for (int idx = blockIdx.x * 256 + threadIdx.x; idx < TOT; idx += 524288) {
    const float* s; ushort* d; int c;
    if (idx < XC) { s = x; d = xb; c = idx; }
    else {
      int r = idx - XC; int w = r >> 18; c = r & 262143;
      switch (w) {
        case 0:  s = Wq;  d = wcat;           break;
        case 1:  s = Wk;  d = wcat + 1*MEG;   break;
        case 2:  s = Wv;  d = wcat + 4*MEG;   break;
        case 3:  s = Wq2; d = wcat + 2*MEG;   break;
        case 4:  s = Wk2; d = wcat + 3*MEG;   break;
        default: s = Wo;  d = wcat + 5*MEG;   break;
      }
    }
    float4 v = *(const float4*)(s + (size_t)c * 4);
    ushort4 o; o.x = f2bf(v.x); o.y = f2bf(v.y); o.z = f2bf(v.z); o.w = f2bf(v.w);
    *(ushort4*)(d + (size_t)c * 4) = o;
  }
}

// ---------------- generic bf16 B^T GEMM (global_load_lds staging) ----------------
#define BM 128
#define BN 128
#define BKK 32

template<int EPI>
__global__ __launch_bounds__(256, 2)
void gemm_bt(const ushort* __restrict__ A, const ushort* __restrict__ Bt,
             void* __restrict__ Cout,
             int M, int N, int K, int lda, int ldb, int ldc,
             long sA1, long sA2, long sB1, long sB2, long sC1, long sC2,
             float scale)
{
  __shared__ ushort a_s[BM * BKK];
  __shared__ ushort b_s[BN * BKK];

  const int z = blockIdx.z, zh = z >> 4, zl = z & 15;
  A  += (size_t)zh * sA1 + (size_t)zl * sA2;
  Bt += (size_t)zh * sB1 + (size_t)zl * sB2;

  const int n0 = blockIdx.x * BN;
  const int m0 = blockIdx.y * BM;

  const int t  = threadIdx.x;
  const int w  = t >> 6, l = t & 63;
  const int wr = w >> 1, wc = w & 1;
  const int l15 = l & 15, l4 = l >> 4;

  const int rs = l >> 2;
  const int c8 = (l & 3) * 8;

  f32x4 acc[4][4] = {};

  for (int k0 = 0; k0 < K; k0 += BKK) {
    #pragma unroll
    for (int j = 0; j < 2; ++j) {
      int ch = w * 2 + j;
      int r  = ch * 16 + rs;
      gl_lds16(&A [(size_t)(m0 + r) * lda + k0 + c8], &a_s[ch * 512]);
      gl_lds16(&Bt[(size_t)(n0 + r) * ldb + k0 + c8], &b_s[ch * 512]);
    }
    __syncthreads();

    bf16x8 af[4], bfr[4];
    #pragma unroll
    for (int mi = 0; mi < 4; ++mi)
      af[mi] = *(const bf16x8*)&a_s[(wr * 64 + mi * 16 + l15) * BKK + l4 * 8];
    #pragma unroll
    for (int ni = 0; ni < 4; ++ni)
      bfr[ni] = *(const bf16x8*)&b_s[(wc * 64 + ni * 16 + l15) * BKK + l4 * 8];

    #pragma unroll
    for (int mi = 0; mi < 4; ++mi)
      #pragma unroll
      for (int ni = 0; ni < 4; ++ni)
        acc[mi][ni] = MFMA(af[mi], bfr[ni], acc[mi][ni]);

    __syncthreads();
  }

  #pragma unroll
  for (int mi = 0; mi < 4; ++mi) {
    #pragma unroll
    for (int ni = 0; ni < 4; ++ni) {
      int col  = n0 + wc * 64 + ni * 16 + l15;
      int row0 = m0 + wr * 64 + mi * 16 + l4 * 4;
      if (EPI == 0) {
        ushort* C = (ushort*)Cout + (size_t)zh * sC1 + (size_t)zl * sC2;
        #pragma unroll
        for (int e = 0; e < 4; ++e)
          C[(size_t)(row0 + e) * ldc + col] = f2bf(acc[mi][ni][e] * scale);
      } else {
        float* C = (float*)Cout + (size_t)zh * sC1 + (size_t)zl * sC2;
        #pragma unroll
        for (int e = 0; e < 4; ++e)
          C[(size_t)(row0 + e) * ldc + col] = acc[mi][ni][e] * scale;
      }
    }
  }
}

// ---------------- fused projection GEMM: [x]@[Wq;Wk;Wq2;Wk2;Wv]^T ----------------
// seg 0..3 -> q/k/q2/k2 row-major (q,q2 pre-scaled by 1/8, exact in bf16);
// seg 1,3 additionally write transposed K/K2 ([z][64][T], like V) for the gram kernel;
// seg 4 -> V transposed per head.
__global__ __launch_bounds__(256, 2)
void gemm_proj(const ushort* __restrict__ A, const ushort* __restrict__ Bt,
               ushort* __restrict__ qb, ushort* __restrict__ kb,
               ushort* __restrict__ q2b, ushort* __restrict__ k2b,
               ushort* __restrict__ vtb,
               ushort* __restrict__ ktb, ushort* __restrict__ k2tb)
{
  __shared__ ushort a_s[BM * BKK];
  __shared__ ushort b_s[BN * BKK];

  const int n0 = blockIdx.x * BN;
  const int m0 = blockIdx.y * BM;

  const int t  = threadIdx.x;
  const int w  = t >> 6, l = t & 63;
  const int wr = w >> 1, wc = w & 1;
  const int l15 = l & 15, l4 = l >> 4;

  const int rs = l >> 2;
  const int c8 = (l & 3) * 8;

  f32x4 acc[4][4] = {};

  for (int k0 = 0; k0 < CS; k0 += BKK) {
    #pragma unroll
    for (int j = 0; j < 2; ++j) {
      int ch = w * 2 + j;
      int r  = ch * 16 + rs;
      gl_lds16(&A [(size_t)(m0 + r) * CS + k0 + c8], &a_s[ch * 512]);
      gl_lds16(&Bt[(size_t)(n0 + r) * CS + k0 + c8], &b_s[ch * 512]);
    }
    __syncthreads();

    bf16x8 af[4], bfr[4];
    #pragma unroll
    for (int mi = 0; mi < 4; ++mi)
      af[mi] = *(const bf16x8*)&a_s[(wr * 64 + mi * 16 + l15) * BKK + l4 * 8];
    #pragma unroll
    for (int ni = 0; ni < 4; ++ni)
      bfr[ni] = *(const bf16x8*)&b_s[(wc * 64 + ni * 16 + l15) * BKK + l4 * 8];

    #pragma unroll
    for (int mi = 0; mi < 4; ++mi)
      #pragma unroll
      for (int ni = 0; ni < 4; ++ni)
        acc[mi][ni] = MFMA(af[mi], bfr[ni], acc[mi][ni]);

    __syncthreads();
  }

  #pragma unroll
  for (int mi = 0; mi < 4; ++mi) {
    #pragma unroll
    for (int ni = 0; ni < 4; ++ni) {
      int col  = n0 + wc * 64 + ni * 16 + l15;
      int row0 = m0 + wr * 64 + mi * 16 + l4 * 4;
      int seg  = col >> 10, cc = col & (CS - 1);
      if (seg < 4) {
        ushort* dst = (seg == 0) ? qb : (seg == 1) ? kb : (seg == 2) ? q2b : k2b;
        float sc = (seg & 1) ? 1.f : 0.125f;   // fold 1/sqrt(Dh) into q, q2
        #pragma unroll
        for (int e = 0; e < 4; ++e)
          dst[(size_t)(row0 + e) * CS + cc] = f2bf(acc[mi][ni][e] * sc);
        if (seg == 1 || seg == 3) {
          int bb = row0 >> 10, tt = row0 & (TS - 1);
          int hh = cc >> 6, dd = cc & (DHEAD - 1);
          ushort* td = (seg == 1) ? ktb : k2tb;
          ushort4 o;
          o.x = f2bf(acc[mi][ni][0]); o.y = f2bf(acc[mi][ni][1]);
          o.z = f2bf(acc[mi][ni][2]); o.w = f2bf(acc[mi][ni][3]);
          *(ushort4*)&td[(((size_t)(bb * NH + hh) * DHEAD + dd) * TS) + tt] = o;
        }
      } else {
        int bb = row0 >> 10, tt = row0 & (TS - 1);
        int hh = cc >> 6, dd = cc & (DHEAD - 1);
        ushort4 o;
        o.x = f2bf(acc[mi][ni][0]); o.y = f2bf(acc[mi][ni][1]);
        o.z = f2bf(acc[mi][ni][2]); o.w = f2bf(acc[mi][ni][3]);
        *(ushort4*)&vtb[(((size_t)(bb * NH + hh) * DHEAD + dd) * TS) + tt] = o;
      }
    }
  }
}

// ---------------- Gram kernel: G = K^T K (64x64, bf16 out) + colsum(K) ----------
// grid = 64: blockIdx.x = z*2 + mat. Reads transposed K layout [z][64 d][T].
__global__ __launch_bounds__(256, 2)
void gram(const ushort* __restrict__ ktb, const ushort* __restrict__ k2tb,
          ushort* __restrict__ g1b, ushort* __restrict__ g2b,
          float* __restrict__ csb)
{
  __shared__ ushort t_s[64 * 128];   // [64 d][128 t], granule-swizzled g ^= d&15

  const int mat = blockIdx.x & 1, z = blockIdx.x >> 1;
  const ushort* S = (mat ? k2tb : ktb) + (size_t)z * DHEAD * TS;

  const int t = threadIdx.x, w = t >> 6, l = t & 63;
  const int l15 = l & 15, l4 = l >> 4;

  f32x4 acc[4] = {};
  float csacc = 0.f;

  for (int tt = 0; tt < 8; ++tt) {
    const int t0 = tt * 128;
    __syncthreads();
    #pragma unroll
    for (int i = 0; i < 4; ++i) {
      int issue = w * 4 + i;
      int row = issue * 4 + l4;
      int gs  = l15 ^ (row & 15);
      gl_lds16(&S[(size_t)row * TS + t0 + gs * 8], &t_s[issue * 512]);
    }
    __syncthreads();

    // colsum partial: lane handles row w*16+l15, t-granules l4*4..+3
    {
      int r = w * 16 + l15;
      #pragma unroll
      for (int j = 0; j < 4; ++j) {
        int gg = ((l4 * 4 + j) ^ (r & 15)) * 8;
        uint4 vv = *(const uint4*)&t_s[r * 128 + gg];
        const ushort* pu = (const ushort*)&vv;
        #pragma unroll
        for (int e2 = 0; e2 < 8; ++e2) csacc += bf2f(pu[e2]);
      }
    }

    #pragma unroll
    for (int ks = 0; ks < 4; ++ks) {
      int ar = w * 16 + l15;
      bf16x8 af = *(const bf16x8*)&t_s[ar * 128 + ((ks * 4 + l4) ^ (ar & 15)) * 8];
      #pragma unroll
      for (int ni = 0; ni < 4; ++ni) {
        int br = ni * 16 + l15;
        bf16x8 bf_ = *(const bf16x8*)&t_s[br * 128 + ((ks * 4 + l4) ^ (br & 15)) * 8];
        acc[ni] = MFMA(af, bf_, acc[ni]);
      }
    }
  }

  csacc += __shfl_xor(csacc, 16);
  csacc += __shfl_xor(csacc, 32);
  if (l4 == 0)
    csb[(mat * 32 + z) * 64 + w * 16 + l15] = csacc;

  ushort* G = (mat ? g2b : g1b) + (size_t)z * 4096;
  #pragma unroll
  for (int ni = 0; ni < 4; ++ni)
    #pragma unroll
    for (int e = 0; e < 4; ++e)
      G[(w * 16 + l4 * 4 + e) * 64 + ni * 16 + l15] = f2bf(acc[ni][e]);
}

// ---------------- fused attention v4: no-max softmax + swapped QK^T ----------------
// Scores are z-scored => |s| <= 32*(0.993 + 0.0067*32) ~ 38.6 for this gate,
// so exp(s) fits fp32/bf16 with huge margin: skip the running max entirely.
// Tiles become order-free sums; lrow reduced once at the end.
// Swapped MFMA (K as A-operand, Q as B): lane holds ONE q-row (l15) x 16 kv,
// mu/iv are per-lane scalars, P packed via v_cvt_pk_bf16_f32 (8B stores).
// Complementary pairing: blocks idx and idx+256 (same CU) get qt pairs summing 15.
__global__ __launch_bounds__(256, 2)
void attn_fused(const ushort* __restrict__ qb, const ushort* __restrict__ kb,
                const ushort* __restrict__ q2b, const ushort* __restrict__ k2b,
                const ushort* __restrict__ vtb, ushort* __restrict__ yb,
                const ushort* __restrict__ g1b, const ushort* __restrict__ g2b,
                const float* __restrict__ csb,
                const float* __restrict__ mixture, const float* __restrict__ qsc)
{
  __shared__ ushort kbuf [2][4096];  // K tile  [64 t][64 d] swz g^=t&7  (buf0: Q in phase A)
  __shared__ ushort k2buf[2][4096];  // K2 tile                          (buf0: Q2 in phase A)
  __shared__ ushort vbuf [2][4096];  // V tile  [64 d][64 t] swz g^=d&7  (buf0: G1 in phase A)
  __shared__ ushort p_s  [64 * 68];  // P tile [64 r][64+4 pad]          (G2 in phase A)
  __shared__ float  statf[128];      // cs1 | cs2 for this head
  __shared__ float  statl[64];       // lrow redistribution (epilogue)

  const int idx  = blockIdx.x;
  const int pp   = idx >> 8;                     // sweep: 0 = big tiles, 1 = small
  const int base = idx & 255;
  const int xcd  = base & 7;
  const int mm   = base >> 3;                    // 0..31
  const int qh   = mm & 7;
  const int z    = (mm >> 3) * 8 + xcd;          // head id, affine to XCD
  const int qt   = pp ? qh : (15 - qh);          // pair (15-qh, qh): sums 15
  const int b    = z >> 4, h = z & 15;
  const int m0   = qt * 64;

  const ushort* Q  = qb  + (size_t)b * TS * CS + h * DHEAD;
  const ushort* Q2 = q2b + (size_t)b * TS * CS + h * DHEAD;
  const ushort* K  = kb  + (size_t)b * TS * CS + h * DHEAD;
  const ushort* K2 = k2b + (size_t)b * TS * CS + h * DHEAD;
  const ushort* Vt = vtb + (size_t)z * DHEAD * TS;
  const ushort* G1 = g1b + (size_t)z * 4096;
  const ushort* G2 = g2b + (size_t)z * 4096;
  ushort* Y = yb + (size_t)b * TS * CS + h * DHEAD;

  const int t = threadIdx.x, w = t >> 6, l = t & 63;
  const int l15 = l & 15, l4 = l >> 4;
  const int r8 = l >> 3, g7 = l & 7;
  const int qrow = w * 16 + l15;                 // this lane's q-row (local)

  const float L2E = 1.44269504f;
  const float gm = 1.f / (1.f + __expf(-mixture[0]));
  const float mq2 = gm * qsc[0] * L2E;           // fold log2(e) into gate
  const float om2 = (1.f - gm) * L2E;

  auto stage_tile = [&](int ct, int bs) {
    const int t0 = ct * 64;
    #pragma unroll
    for (int i = 0; i < 2; ++i) {
      int issue = w * 2 + i;
      int row = issue * 8 + r8;
      int gs  = g7 ^ (row & 7);
      gl_lds16(&K [(size_t)(t0 + row) * CS + gs * 8], &kbuf [bs][issue * 512]);
      gl_lds16(&K2[(size_t)(t0 + row) * CS + gs * 8], &k2buf[bs][issue * 512]);
      gl_lds16(&Vt[(size_t)row * TS + t0 + gs * 8], &vbuf[bs][issue * 512]);
    }
  };

  // ---- phase A: stage cs (f32), Q,Q2,G1 -> buf0, G2 -> p_s; tile0 -> buf1 ----
  if (t < 64)       statf[t]      = csb[z * 64 + t];
  else if (t < 128) statf[t]      = csb[2048 + z * 64 + (t - 64)];
  #pragma unroll
  for (int i = 0; i < 2; ++i) {
    int issue = w * 2 + i;
    int row = issue * 8 + r8;
    int gs  = g7 ^ (row & 7);
    gl_lds16(&Q [(size_t)(m0 + row) * CS + gs * 8], &kbuf [0][issue * 512]);
    gl_lds16(&Q2[(size_t)(m0 + row) * CS + gs * 8], &k2buf[0][issue * 512]);
    gl_lds16(&G1[row * 64 + gs * 8], &vbuf[0][issue * 512]);
    gl_lds16(&G2[row * 64 + gs * 8], &p_s[issue * 512]);
  }
  stage_tile(0, 1);
  __syncthreads();

  // Q fragments (16 rows over l15, k-slice over l4)
  bf16x8 fq[2], fq2[2];
  #pragma unroll
  for (int ks = 0; ks < 2; ++ks) {
    int gg = ((ks * 4 + l4) ^ (qrow & 7)) * 8;
    fq [ks] = *(const bf16x8*)&kbuf [0][qrow * 64 + gg];
    fq2[ks] = *(const bf16x8*)&k2buf[0][qrow * 64 + gg];
  }

  // U = G @ Q^T (swapped): lane: q = qrow (scalar), d = ni*16 + l4*4 + e
  f32x4 U1[4] = {}, U2[4] = {};
  #pragma unroll
  for (int ks = 0; ks < 2; ++ks) {
    #pragma unroll
    for (int ni = 0; ni < 4; ++ni) {
      int gr = ni * 16 + l15;
      int gg = ((ks * 4 + l4) ^ (gr & 7)) * 8;
      bf16x8 bg1 = *(const bf16x8*)&vbuf[0][gr * 64 + gg];
      bf16x8 bg2 = *(const bf16x8*)&p_s[gr * 64 + gg];
      U1[ni] = MFMA(bg1, fq [ks], U1[ni]);
      U2[ni] = MFMA(bg2, fq2[ks], U2[ni]);
    }
  }

  // per-lane scalar stats: ssq = sum_d U[d]*q[d] ; mudot = sum_d q[d]*cs[d]
  float ssq1 = 0.f, md1 = 0.f, ssq2 = 0.f, md2 = 0.f;
  #pragma unroll
  for (int ni = 0; ni < 4; ++ni) {
    int gsq = ((ni * 2 + (l4 >> 1)) ^ (qrow & 7));
    int off = qrow * 64 + gsq * 8 + (l4 & 1) * 4;
    ushort qa[4], qb2[4];
    *(uint2*)qa  = *(const uint2*)&kbuf [0][off];
    *(uint2*)qb2 = *(const uint2*)&k2buf[0][off];
    float c1[4], c2[4];
    *(float4*)c1 = *(const float4*)&statf[ni * 16 + l4 * 4];
    *(float4*)c2 = *(const float4*)&statf[64 + ni * 16 + l4 * 4];
    #pragma unroll
    for (int e = 0; e < 4; ++e) {
      float qv1 = bf2f(qa[e]), qv2 = bf2f(qb2[e]);
      ssq1 = fmaf(U1[ni][e], qv1, ssq1); md1 = fmaf(qv1, c1[e], md1);
      ssq2 = fmaf(U2[ni][e], qv2, ssq2); md2 = fmaf(qv2, c2[e], md2);
    }
  }
  ssq1 += __shfl_xor(ssq1, 16); md1 += __shfl_xor(md1, 16);
  ssq2 += __shfl_xor(ssq2, 16); md2 += __shfl_xor(md2, 16);
  ssq1 += __shfl_xor(ssq1, 32); md1 += __shfl_xor(md1, 32);
  ssq2 += __shfl_xor(ssq2, 32); md2 += __shfl_xor(md2, 32);

  const float mu1 = md1 * (1.f / TS), mu2 = md2 * (1.f / TS);
  const float va1 = (ssq1 - (float)TS * mu1 * mu1) * (1.f / (TS - 1));
  const float va2 = (ssq2 - (float)TS * mu2 * mu2) * (1.f / (TS - 1));
  const float iv1 = 1.f / (sqrtf(fmaxf(va1, 0.f)) + EPSV);
  const float iv2 = 1.f / (sqrtf(fmaxf(va2, 0.f)) + EPSV);
  __syncthreads();                   // all waves done reading buf0 / p_s(G2)

  // ---- tile loop: prefetch(t+1) -> compute(t) -> barrier ----
  float lrow = 0.f;
  f32x4 accO[4] = {};                // lane: q = (l4,e), d = ni*16+l15

  for (int ct = 0; ct <= qt; ++ct) {
    const int cur = (ct & 1) ^ 1;    // tile0 in buf1, tile1 in buf0, ...
    if (ct < qt) stage_tile(ct + 1, cur ^ 1);

    const ushort* ks_ = kbuf [cur];
    const ushort* k2s_= k2buf[cur];
    const ushort* vs_ = vbuf [cur];

    // QK^T swapped: lane: q = qrow, kv = ni*16 + l4*4 + e
    f32x4 a1[4] = {}, a2[4] = {};
    #pragma unroll
    for (int ks = 0; ks < 2; ++ks) {
      bf16x8 bk[4], bk2[4];
      #pragma unroll
      for (int ni = 0; ni < 4; ++ni) {
        int j  = ni * 16 + l15;
        int gg = ((ks * 4 + l4) ^ (j & 7)) * 8;
        bk [ni] = *(const bf16x8*)&ks_ [j * 64 + gg];
        bk2[ni] = *(const bf16x8*)&k2s_[j * 64 + gg];
      }
      #pragma unroll
      for (int ni = 0; ni < 4; ++ni) {
        a1[ni] = MFMA(bk [ni], fq [ks], a1[ni]);
        a2[ni] = MFMA(bk2[ni], fq2[ks], a2[ni]);
      }
    }

    // normalize + gate (+ mask on diagonal tile) + exp2; pack & store P
    const bool diag = (ct == qt);
    #pragma unroll
    for (int ni = 0; ni < 4; ++ni) {
      float pe[4];
      #pragma unroll
      for (int e = 0; e < 4; ++e) {
        float n1 = (a1[ni][e] - mu1) * iv1;
        float n2 = (a2[ni][e] - mu2) * iv2;
        float sc = n1 * fmaf(mq2, n2, om2);
        float pv = exp2f(sc);
        if (diag) pv = ((ni * 16 + l4 * 4 + e) <= qrow) ? pv : 0.f;
        lrow += pv;
        pe[e] = pv;
      }
      uint32_t pk01, pk23;
      asm("v_cvt_pk_bf16_f32 %0, %1, %2" : "=v"(pk01) : "v"(pe[0]), "v"(pe[1]));
      asm("v_cvt_pk_bf16_f32 %0, %1, %2" : "=v"(pk23) : "v"(pe[2]), "v"(pe[3]));
      uint2 pk; pk.x = pk01; pk.y = pk23;
      *(uint2*)&p_s[qrow * 68 + ni * 16 + l4 * 4] = pk;
    }

    // PV: wave-local P rows (same-wave lgkmcnt ordering; no barrier)
    #pragma unroll
    for (int ks = 0; ks < 2; ++ks) {
      int po = qrow * 68 + ks * 32 + l4 * 8;
      bf16x4 plo = *(const bf16x4*)&p_s[po];
      bf16x4 phi = *(const bf16x4*)&p_s[po + 4];
      bf16x8 ap = __builtin_shufflevector(plo, phi, 0, 1, 2, 3, 4, 5, 6, 7);
      bf16x8 bv[4];
      #pragma unroll
      for (int ni = 0; ni < 4; ++ni) {
        int d  = ni * 16 + l15;
        int gg = ((ks * 4 + l4) ^ (d & 7)) * 8;
        bv[ni] = *(const bf16x8*)&vs_[d * 64 + gg];
      }
      #pragma unroll
      for (int ni = 0; ni < 4; ++ni)
        accO[ni] = MFMA(ap, bv[ni], accO[ni]);
    }

    __syncthreads();   // drains prefetch (issued pre-compute) + releases cur
  }

  // ---- epilogue: reduce lrow over l4 group, redistribute, O/l -> yb ----
  lrow += __shfl_xor(lrow, 16);
  lrow += __shfl_xor(lrow, 32);
  if (l4 == 0) statl[qrow] = lrow;
  float il[4];
  *(float4*)il = *(const float4*)&statl[w * 16 + l4 * 4];
  #pragma unroll
  for (int e = 0; e < 4; ++e) il[e] = 1.f / il[e];
  #pragma unroll
  for (int ni = 0; ni < 4; ++ni)
    #pragma unroll
    for (int e = 0; e < 4; ++e)
      Y[(size_t)(m0 + w * 16 + l4 * 4 + e) * CS + ni * 16 + l15] =
          f2bf(accO[ni][e] * il[e]);
}

// ---------------- launcher ----------------
extern "C" void kernel_launch(void* const* d_in, const int* in_sizes, int n_in,
                              void* d_out, int out_size, void* d_ws, size_t ws_size,
                              hipStream_t stream) {
  const float* x    = (const float*)d_in[0];
  const float* Wq   = (const float*)d_in[1];
  const float* Wk   = (const float*)d_in[2];
  const float* Wv   = (const float*)d_in[3];
  const float* Wq2  = (const float*)d_in[4];
  const float* Wk2  = (const float*)d_in[5];
  const float* Wo   = (const float*)d_in[6];
  const float* mixture = (const float*)d_in[7];
  const float* qsc  = (const float*)d_in[8];
  float* out = (float*)d_out;

  const size_t MT = (size_t)NBATCH * TS;   // 2048
  ushort* ws = (ushort*)d_ws;
  ushort* xb   = ws;                                  // 2M
  ushort* wcat = xb   + (size_t)2 * MEG;              // 6M: wq,wk,wq2,wk2,wv,wo
  ushort* qb   = wcat + (size_t)6 * MEG;              // 2M (pre-scaled by 1/8)
  ushort* q2b  = qb   + (size_t)2 * MEG;              // 2M (pre-scaled by 1/8)
  ushort* kb   = q2b  + (size_t)2 * MEG;              // 2M
  ushort* k2b  = kb   + (size_t)2 * MEG;              // 2M
  ushort* vtb  = k2b  + (size_t)2 * MEG;              // 2M  [B*NH][64][T]
  ushort* yb   = vtb  + (size_t)2 * MEG;              // 2M
  ushort* ktb  = yb   + (size_t)2 * MEG;              // 2M  [B*NH][64][T]
  ushort* k2tb = ktb  + (size_t)2 * MEG;              // 2M
  ushort* g1b  = k2tb + (size_t)2 * MEG;              // 128K: [32][64][64] bf16
  ushort* g2b  = g1b  + (size_t)(MEG / 8);            // 128K
  float*  csb  = (float*)(g2b + (size_t)(MEG / 8));   // [2][32][64] fp32
  ushort* wob  = wcat + (size_t)5 * MEG;

  // 1. cast everything to bf16
  cast_all<<<2048, 256, 0, stream>>>(x, Wq, Wk, Wv, Wq2, Wk2, Wo, xb, wcat);

  // 2. fused projections (+ transposed K, K2 for gram)
  gemm_proj<<<dim3(5 * CS / BN, MT / BM, 1), 256, 0, stream>>>(
      xb, wcat, qb, kb, q2b, k2b, vtb, ktb, k2tb);

  // 3. Gram matrices + colsums (row-stat shortcut: sum s = q.cs ; sum s^2 = q^T G q)
  gram<<<64, 256, 0, stream>>>(ktb, k2tb, g1b, g2b, csb);

  // 4. fused attention (no-max softmax, complementary pairing)
  attn_fused<<<512, 256, 0, stream>>>(qb, kb, q2b, k2b, vtb, yb,
                                      g1b, g2b, csb, mixture, qsc);

  // 5. output projection (fp32 out)
  gemm_bt<1><<<dim3(CS / BN, MT / BM, 1), 256, 0, stream>>>(
      yb, wob, out, (int)MT, CS, CS, CS, CS, CS, 0, 0, 0, 0, 0, 0, 1.f);
}